// Round 9
// baseline (205.623 us; speedup 1.0000x reference)
//
#include <hip/hip_runtime.h>

typedef __bf16 bf16;
typedef __attribute__((ext_vector_type(8))) __bf16 bf16x8;
typedef __attribute__((ext_vector_type(2))) __bf16 bf16x2;
typedef __attribute__((ext_vector_type(4))) float f32x4;

#define AS1 __attribute__((address_space(1)))
#define AS3 __attribute__((address_space(3)))

// Problem constants
#define BB 2
#define SS 2048
#define DD 1024
#define HH 16
#define HD 64
#define BH (BB*HH)

// 0.125 (1/sqrt(64)) * 1/ln(2): folded into Q so scores come out in log2 units
#define QSCALE 0.1803368801111244f

static __device__ __forceinline__ f32x4 mfma16(bf16x8 a, bf16x8 b, f32x4 c) {
  return __builtin_amdgcn_mfma_f32_16x16x32_bf16(a, b, c, 0, 0, 0);
}
static __device__ __forceinline__ float fexp2(float x) {
  return __builtin_amdgcn_exp2f(x);
}

// XCD-aware remap, 512-block grids: all 16 blocks of a bh on one XCD.
static __device__ __forceinline__ void swz512(int bid, int& bh, int& pr) {
  int c = bid & 7, j = bid >> 3;
  bh = c + 8 * (j & 3);
  pr = j >> 2;               // 0..15
}
// XCD-aware remap, 1024-block colz grid: all 32 blocks of a bh on one XCD.
static __device__ __forceinline__ void swz1024(int bid, int& bh, int& strip0, int& qh) {
  int c = bid & 7, j = bid >> 3;
  bh = c + 8 * (j & 3);
  int rem = j >> 2;          // 0..31
  strip0 = rem & 15;
  qh = rem >> 4;
}

// ---------------- fp32 -> bf16 conversion, fused (weights: 4 tensors) ----------------
__global__ __launch_bounds__(256) void cvt_w(const float* __restrict__ s0, const float* __restrict__ s1,
                                             const float* __restrict__ s2, const float* __restrict__ s3,
                                             bf16* __restrict__ o0, bf16* __restrict__ o1,
                                             bf16* __restrict__ o2, bf16* __restrict__ o3) {
  const int z = blockIdx.y;
  const float* s = (z == 0) ? s0 : (z == 1) ? s1 : (z == 2) ? s2 : s3;
  bf16* o = (z == 0) ? o0 : (z == 1) ? o1 : (z == 2) ? o2 : o3;
  int i = blockIdx.x * 256 + threadIdx.x;
  const float4* sp = (const float4*)s;
  float4 a = sp[2 * i], b = sp[2 * i + 1];
  bf16x8 v;
  v[0] = (bf16)a.x; v[1] = (bf16)a.y; v[2] = (bf16)a.z; v[3] = (bf16)a.w;
  v[4] = (bf16)b.x; v[5] = (bf16)b.y; v[6] = (bf16)b.z; v[7] = (bf16)b.w;
  ((bf16x8*)o)[i] = v;
}

// ---------------- fp32 -> bf16 conversion, fused (inputs: 3 tensors) ----------------
__global__ __launch_bounds__(256) void cvt_x(const float* __restrict__ s0, const float* __restrict__ s1,
                                             const float* __restrict__ s2,
                                             bf16* __restrict__ o0, bf16* __restrict__ o1,
                                             bf16* __restrict__ o2) {
  const int z = blockIdx.y;
  const float* s = (z == 0) ? s0 : (z == 1) ? s1 : s2;
  bf16* o = (z == 0) ? o0 : (z == 1) ? o1 : o2;
  int i = blockIdx.x * 256 + threadIdx.x;
  const float4* sp = (const float4*)s;
  float4 a = sp[2 * i], b = sp[2 * i + 1];
  bf16x8 v;
  v[0] = (bf16)a.x; v[1] = (bf16)a.y; v[2] = (bf16)a.z; v[3] = (bf16)a.w;
  v[4] = (bf16)b.x; v[5] = (bf16)b.y; v[6] = (bf16)b.z; v[7] = (bf16)b.w;
  ((bf16x8*)o)[i] = v;
}

// ---------------- core 128x128 bf16 NT GEMM (C = A * B^T), K mult of 32 ----------------
__device__ __forceinline__ void gemm_core(const bf16* __restrict__ A,
                                          const bf16* __restrict__ Bm, int K,
                                          int m0, int n0, int w, int l,
                                          bf16* sA, bf16* sB, f32x4 (&acc)[4][4]) {
  const int l15 = l & 15, lg = l >> 4;
  const int wr = (w >> 1) * 64, wc = (w & 1) * 64;
  for (int kt = 0; kt < K; kt += 32) {
#pragma unroll
    for (int i = 0; i < 2; ++i) {
      int t = i * 256 + w * 64 + l;
      const bf16* ga = A + (size_t)(m0 + (t >> 2)) * K + kt + (t & 3) * 8;
      const bf16* gb = Bm + (size_t)(n0 + (t >> 2)) * K + kt + (t & 3) * 8;
      __builtin_amdgcn_global_load_lds((const AS1 void*)ga,
                                       (AS3 void*)(sA + (i * 256 + w * 64) * 8), 16, 0, 0);
      __builtin_amdgcn_global_load_lds((const AS1 void*)gb,
                                       (AS3 void*)(sB + (i * 256 + w * 64) * 8), 16, 0, 0);
    }
    __syncthreads();
    bf16x8 af[4], bfr[4];
#pragma unroll
    for (int m = 0; m < 4; ++m)
      af[m] = *(const bf16x8*)(sA + (wr + m * 16 + l15) * 32 + lg * 8);
#pragma unroll
    for (int n = 0; n < 4; ++n)
      bfr[n] = *(const bf16x8*)(sB + (wc + n * 16 + l15) * 32 + lg * 8);
#pragma unroll
    for (int m = 0; m < 4; ++m)
#pragma unroll
      for (int n = 0; n < 4; ++n)
        acc[m][n] = mfma16(af[m], bfr[n], acc[m][n]);
    __syncthreads();
  }
}

// ---------------- batched QKV projection: y = x @ W^T + b, heads layout ----------------
// z=0: Q (prescaled by QSCALE) -> [BH][S][64]; z=1: K -> [BH][S][64]; z=2: V -> [BH][64][S]
__global__ __launch_bounds__(256) void proj_gemm(
    const bf16* __restrict__ Xq, const bf16* __restrict__ Xk, const bf16* __restrict__ Xv,
    const bf16* __restrict__ Wq, const bf16* __restrict__ Wk, const bf16* __restrict__ Wv,
    const float* __restrict__ bq, const float* __restrict__ bk, const float* __restrict__ bv,
    bf16* __restrict__ Oq, bf16* __restrict__ Ok, bf16* __restrict__ Ovt) {
  __shared__ __align__(16) bf16 sA[128 * 32];
  __shared__ __align__(16) bf16 sB[128 * 32];
  const int z = blockIdx.z;
  const bf16* A = (z == 0) ? Xq : ((z == 1) ? Xk : Xv);
  const bf16* W = (z == 0) ? Wq : ((z == 1) ? Wk : Wv);
  const float* bias = (z == 0) ? bq : ((z == 1) ? bk : bv);
  const int tid = threadIdx.x, l = tid & 63, w = tid >> 6;
  const int m0 = blockIdx.y * 128, n0 = blockIdx.x * 128;
  f32x4 acc[4][4] = {};
  gemm_core(A, W, DD, m0, n0, w, l, sA, sB, acc);
  const int l15 = l & 15, lg = l >> 4;
  const int wr = (w >> 1) * 64, wc = (w & 1) * 64;
#pragma unroll
  for (int n = 0; n < 4; ++n) {
    int col = n0 + wc + n * 16 + l15;
    float bb = bias[col];
    int h = col >> 6, d = col & 63;
#pragma unroll
    for (int m = 0; m < 4; ++m) {
#pragma unroll
      for (int r = 0; r < 4; ++r) {
        int row = m0 + wr + m * 16 + lg * 4 + r;
        int b = row >> 11, s = row & (SS - 1);
        float vv = acc[m][n][r] + bb;
        if (z == 0) vv *= QSCALE;
        if (z != 2)
          ((z == 0) ? Oq : Ok)[(((size_t)(b * HH + h)) * SS + s) * HD + d] = (bf16)vv;
        else
          Ovt[(((size_t)(b * HH + h)) * HD + d) * SS + s] = (bf16)vv;
      }
    }
  }
}

// ---------------- output projection: out = ctx @ Wo^T + bo (fp32 out) ----------------
__global__ __launch_bounds__(256) void out_gemm(const bf16* __restrict__ A,
                                                const bf16* __restrict__ W,
                                                const float* __restrict__ bias,
                                                float* __restrict__ out) {
  __shared__ __align__(16) bf16 sA[128 * 32];
  __shared__ __align__(16) bf16 sB[128 * 32];
  const int tid = threadIdx.x, l = tid & 63, w = tid >> 6;
  const int m0 = blockIdx.y * 128, n0 = blockIdx.x * 128;
  f32x4 acc[4][4] = {};
  gemm_core(A, W, DD, m0, n0, w, l, sA, sB, acc);
  const int l15 = l & 15, lg = l >> 4;
  const int wr = (w >> 1) * 64, wc = (w & 1) * 64;
#pragma unroll
  for (int n = 0; n < 4; ++n) {
    int col = n0 + wc + n * 16 + l15;
    float bb = bias[col];
#pragma unroll
    for (int m = 0; m < 4; ++m)
#pragma unroll
      for (int r = 0; r < 4; ++r) {
        int row = m0 + wr + m * 16 + lg * 4 + r;
        out[(size_t)row * DD + col] = acc[m][n][r] + bb;
      }
  }
}

// ---------------- pass A: per-column partial softmax denominator -----------------------
__global__ __launch_bounds__(256) void colz(const bf16* __restrict__ Qb,
                                            const bf16* __restrict__ Kb,
                                            float* __restrict__ zPart) {
  __shared__ float zred[4][64];
  int bh, pair, qh;
  swz1024(blockIdx.x, bh, pair, qh);
  const int tid = threadIdx.x, l = tid & 63, w = tid >> 6;
  const int l15 = l & 15, lg = l >> 4;
  const bf16* Q = Qb + (size_t)bh * SS * HD;
  const bf16* Kh = Kb + (size_t)bh * SS * HD;

  for (int half = 0; half < 2; ++half) {
    const int s = half ? (31 - pair) : pair;
    const int c0 = s * 64;
    bf16x8 kf[4][2];
#pragma unroll
    for (int kt = 0; kt < 4; ++kt) {
      kf[kt][0] = *(const bf16x8*)&Kh[(c0 + kt * 16 + l15) * HD + lg * 8];
      kf[kt][1] = *(const bf16x8*)&Kh[(c0 + kt * 16 + l15) * HD + 32 + lg * 8];
    }
    float z[4] = {};
    const int qstart = c0 + qh * 64 + w * 16;
    bf16x8 qa0, qa1, qn0, qn1;
    if (qstart < SS) {
      qa0 = *(const bf16x8*)&Q[(qstart + l15) * HD + lg * 8];
      qa1 = *(const bf16x8*)&Q[(qstart + l15) * HD + 32 + lg * 8];
    }
    for (int qb = qstart; qb < SS; qb += 128) {
      const int qnext = qb + 128;
      if (qnext < SS) {
        qn0 = *(const bf16x8*)&Q[(qnext + l15) * HD + lg * 8];
        qn1 = *(const bf16x8*)&Q[(qnext + l15) * HD + 32 + lg * 8];
      }
      f32x4 d[4] = {};
#pragma unroll
      for (int kt = 0; kt < 4; ++kt) {
        d[kt] = mfma16(qa0, kf[kt][0], d[kt]);
        d[kt] = mfma16(qa1, kf[kt][1], d[kt]);
      }
#pragma unroll
      for (int kt = 0; kt < 4; ++kt) {
        const int kcol = c0 + kt * 16 + l15;
#pragma unroll
        for (int r = 0; r < 4; ++r) {
          int qq = qb + lg * 4 + r;
          z[kt] += (qq > kcol) ? fexp2(d[kt][r]) : 0.f;
        }
      }
      qa0 = qn0; qa1 = qn1;
    }
#pragma unroll
    for (int kt = 0; kt < 4; ++kt) {
      z[kt] += __shfl_xor(z[kt], 16);
      z[kt] += __shfl_xor(z[kt], 32);
    }
    if (l < 16) {
#pragma unroll
      for (int kt = 0; kt < 4; ++kt) zred[w][kt * 16 + l15] = z[kt];
    }
    __syncthreads();
    if (tid < 64) {
      float zs = zred[0][tid] + zred[1][tid] + zred[2][tid] + zred[3][tid];
      zPart[((size_t)qh * BH + bh) * SS + c0 + tid] = zs;
    }
    __syncthreads();
  }
}

// ---------------- combine the two z partials into reciprocal denominators --------------
__global__ __launch_bounds__(256) void rzfin(const float* __restrict__ zPart,
                                             float* __restrict__ cRZ) {
  int i = blockIdx.x * 256 + threadIdx.x;  // f32x4 index over BH*SS
  f32x4 a = ((const f32x4*)zPart)[i];
  f32x4 b = ((const f32x4*)(zPart + (size_t)BH * SS))[i];
  f32x4 r;
#pragma unroll
  for (int j = 0; j < 4; ++j) {
    float s = a[j] + b[j];
    r[j] = (s > 0.f) ? 1.0f / s : 0.f;
  }
  ((f32x4*)cRZ)[i] = r;
}

// ---------------- prescale V columns by rz (in place); save vlast column first ----------
__global__ __launch_bounds__(256) void vscale(bf16* __restrict__ Vt,
                                              const float* __restrict__ cRZ,
                                              float* __restrict__ vlastB) {
  int i = blockIdx.x * 256 + threadIdx.x;  // (bh*64+d) * 256 s-chunks
  int sc = i & (SS / 8 - 1);
  int rest = i >> 8;                       // bh*64 + d
  int s0 = sc * 8;
  bf16* p = Vt + (size_t)rest * SS + s0;
  const float* rz = cRZ + (size_t)(rest >> 6) * SS + s0;
  bf16x8 v = *(const bf16x8*)p;
  if (s0 + 8 == SS) vlastB[rest] = (float)v[7] * (1.0f / (float)SS);
  f32x4 r0 = *(const f32x4*)rz, r1 = *(const f32x4*)(rz + 4);
  bf16x8 o;
#pragma unroll
  for (int j = 0; j < 4; ++j) o[j] = (bf16)((float)v[j] * r0[j]);
#pragma unroll
  for (int j = 0; j < 4; ++j) o[4 + j] = (bf16)((float)v[4 + j] * r1[j]);
  *(bf16x8*)p = o;
}

// ---------------- pass B building blocks ------------------------------------------------
// KV register buffer for one 32-k chunk: 4 K fragments + 4 pi-permuted V' fragments.
struct KV {
  bf16x8 k[4];
  unsigned int v[4][4];
};

static __device__ __forceinline__ void kv_load(KV& b, const bf16* __restrict__ Kh,
                                               const bf16* __restrict__ V, int k0,
                                               int l15, int lg) {
  b.k[0] = *(const bf16x8*)&Kh[(k0 + l15) * HD + lg * 8];
  b.k[1] = *(const bf16x8*)&Kh[(k0 + l15) * HD + 32 + lg * 8];
  b.k[2] = *(const bf16x8*)&Kh[(k0 + 16 + l15) * HD + lg * 8];
  b.k[3] = *(const bf16x8*)&Kh[(k0 + 16 + l15) * HD + 32 + lg * 8];
#pragma unroll
  for (int dt = 0; dt < 4; ++dt) {
    const bf16* vrow = &V[(size_t)(dt * 16 + l15) * SS];
    uint2 lo = *(const uint2*)&vrow[k0 + 4 * lg];
    uint2 hi = *(const uint2*)&vrow[k0 + 16 + 4 * lg];
    b.v[dt][0] = lo.x; b.v[dt][1] = lo.y; b.v[dt][2] = hi.x; b.v[dt][3] = hi.y;
  }
}

// Swapped QK^T (mfma(K,Q)) -> lane holds P[q=l15][k]; packed lane-locally into the PV
// A-fragment under pi(8lg+j) = (j<4 ? 4lg+j : 16+4lg+j-4); V' fragments use the same pi.
// DIAG=false chunks (k0+32 <= q0) are provably fully unmasked -> no compare/select.
template <bool DIAG>
static __device__ __forceinline__ void kv_compute(const KV& b, int k0, int q0,
                                                  const bf16x8 (&qa)[4][2],
                                                  f32x4 (&acc)[4][4], int l15, int lg) {
  const int kb0i = k0 + lg * 4, kb1i = k0 + 16 + lg * 4;
#pragma unroll
  for (int qt = 0; qt < 4; ++qt) {
    f32x4 s0 = {}, s1 = {};
    s0 = mfma16(b.k[0], qa[qt][0], s0);
    s0 = mfma16(b.k[1], qa[qt][1], s0);
    s1 = mfma16(b.k[2], qa[qt][0], s1);
    s1 = mfma16(b.k[3], qa[qt][1], s1);
    const int qq = q0 + qt * 16 + l15;
    union { unsigned int u[4]; bf16x8 v; } pa;
#pragma unroll
    for (int hw = 0; hw < 2; ++hw) {
      bf16x2 t0, t1;
#pragma unroll
      for (int r = 0; r < 2; ++r) {
        int rr = hw * 2 + r;
        float p0 = fexp2(s0[rr]);
        float p1 = fexp2(s1[rr]);
        if (DIAG) {
          p0 = (kb0i + rr < qq) ? p0 : 0.f;
          p1 = (kb1i + rr < qq) ? p1 : 0.f;
        }
        t0[r] = (bf16)p0;
        t1[r] = (bf16)p1;
      }
      pa.u[hw] = __builtin_bit_cast(unsigned int, t0);
      pa.u[hw + 2] = __builtin_bit_cast(unsigned int, t1);
    }
#pragma unroll
    for (int dt = 0; dt < 4; ++dt) {
      union { unsigned int u[4]; bf16x8 v; } vf;
      vf.u[0] = b.v[dt][0]; vf.u[1] = b.v[dt][1];
      vf.u[2] = b.v[dt][2]; vf.u[3] = b.v[dt][3];
      acc[qt][dt] = mfma16(pa.v, vf.v, acc[qt][dt]);
    }
  }
}

// ---------------- pass B: 64q tiles paired (t, 31-t), k-split across 8 waves ------------
// 512-thread blocks, grid 512 -> 2 blocks/CU, 16 waves/CU (4/SIMD) for latency hiding.
// ~8.25 serial chunks/wave. Partials merged via 3-phase 4-buffer LDS tree.
__global__ __launch_bounds__(512, 4) void attn_ctx(const bf16* __restrict__ Qb,
                                                   const bf16* __restrict__ Kb,
                                                   const bf16* __restrict__ Vt,
                                                   const float* __restrict__ vlastB,
                                                   bf16* __restrict__ ctx) {
  __shared__ __align__(16) float red[4][64 * 68];  // [d][q] pitch 68 (69.6 KB)
  int bh, pr;
  swz512(blockIdx.x, bh, pr);
  const int tid = threadIdx.x, l = tid & 63, w = tid >> 6;  // w in 0..7
  const int l15 = l & 15, lg = l >> 4;
  const bf16* Q = Qb + (size_t)bh * SS * HD;
  const bf16* Kh = Kb + (size_t)bh * SS * HD;
  const bf16* V = Vt + (size_t)bh * HD * SS;  // [64][S], rz-prescaled
  const int b = bh >> 4, h = bh & 15;

  float vlast[4];
#pragma unroll
  for (int dt = 0; dt < 4; ++dt) vlast[dt] = vlastB[bh * 64 + dt * 16 + l15];

  for (int half = 0; half < 2; ++half) {
    const int t = half ? (31 - pr) : pr;
    const int q0 = t * 64;

    bf16x8 qa[4][2];
#pragma unroll
    for (int qt = 0; qt < 4; ++qt)
#pragma unroll
      for (int kk = 0; kk < 2; ++kk)
        qa[qt][kk] = *(const bf16x8*)&Q[(q0 + qt * 16 + l15) * HD + kk * 32 + lg * 8];

    f32x4 acc[4][4] = {};  // [qt][dt]
    KV A;
    // unmasked chunks: k0 = w*32 + 256j < q0
    for (int k0 = w * 32; k0 < q0; k0 += 256) {
      kv_load(A, Kh, V, k0, l15, lg);
      kv_compute<false>(A, k0, q0, qa, acc, l15, lg);
    }
    // diagonal chunks k0 = q0, q0+32 -> waves (2t)&7 and (2t+1)&7
    {
      const int cw = (2 * t) & 7;
      int dk = (w == cw) ? q0 : ((w == ((cw + 1) & 7)) ? q0 + 32 : -1);
      if (dk >= 0) {
        kv_load(A, Kh, V, dk, l15, lg);
        kv_compute<true>(A, dk, q0, qa, acc, l15, lg);
      }
    }

    // merge 8 per-wave partials: 3-phase tree (4 bufs)
    // phase 1: waves 4..7 stash; waves 0..3 add
    if (w >= 4) {
      float* buf = red[w - 4];
#pragma unroll
      for (int qt = 0; qt < 4; ++qt)
#pragma unroll
        for (int dt = 0; dt < 4; ++dt)
          *(f32x4*)&buf[(dt * 16 + l15) * 68 + qt * 16 + lg * 4] = acc[qt][dt];
    }
    __syncthreads();
    if (w < 4) {
#pragma unroll
      for (int qt = 0; qt < 4; ++qt)
#pragma unroll
        for (int dt = 0; dt < 4; ++dt)
          acc[qt][dt] += *(const f32x4*)&red[w][(dt * 16 + l15) * 68 + qt * 16 + lg * 4];
    }
    __syncthreads();
    // phase 2: waves 2,3 stash; waves 0,1 add
    if (w == 2 || w == 3) {
      float* buf = red[w - 2];
#pragma unroll
      for (int qt = 0; qt < 4; ++qt)
#pragma unroll
        for (int dt = 0; dt < 4; ++dt)
          *(f32x4*)&buf[(dt * 16 + l15) * 68 + qt * 16 + lg * 4] = acc[qt][dt];
    }
    __syncthreads();
    if (w < 2) {
#pragma unroll
      for (int qt = 0; qt < 4; ++qt)
#pragma unroll
        for (int dt = 0; dt < 4; ++dt)
          acc[qt][dt] += *(const f32x4*)&red[w][(dt * 16 + l15) * 68 + qt * 16 + lg * 4];
    }
    __syncthreads();
    // phase 3: wave 1 stash; wave 0 adds + writes out
    if (w == 1) {
#pragma unroll
      for (int qt = 0; qt < 4; ++qt)
#pragma unroll
        for (int dt = 0; dt < 4; ++dt)
          *(f32x4*)&red[0][(dt * 16 + l15) * 68 + qt * 16 + lg * 4] = acc[qt][dt];
    }
    __syncthreads();
    if (w == 0) {
#pragma unroll
      for (int qt = 0; qt < 4; ++qt) {
#pragma unroll
        for (int dt = 0; dt < 4; ++dt) {
          f32x4 a = acc[qt][dt];
          a += *(const f32x4*)&red[0][(dt * 16 + l15) * 68 + qt * 16 + lg * 4];
#pragma unroll
          for (int r = 0; r < 4; ++r) {
            int q = q0 + qt * 16 + lg * 4 + r;
            ctx[((size_t)(b * SS + q)) * DD + h * HD + dt * 16 + l15] =
                (bf16)(a[r] + vlast[dt]);
          }
        }
      }
    }
    __syncthreads();  // protect red before next half reuses it
  }
}

// ---------------- launcher ----------------
extern "C" void kernel_launch(void* const* d_in, const int* in_sizes, int n_in,
                              void* d_out, int out_size, void* d_ws, size_t ws_size,
                              hipStream_t stream) {
  const float* q  = (const float*)d_in[0];
  const float* k  = (const float*)d_in[1];
  const float* v  = (const float*)d_in[2];
  const float* Wq = (const float*)d_in[3];
  const float* bq = (const float*)d_in[4];
  const float* Wk = (const float*)d_in[5];
  const float* bk = (const float*)d_in[6];
  const float* Wv = (const float*)d_in[7];
  const float* bv = (const float*)d_in[8];
  const float* Wo = (const float*)d_in[9];
  const float* bo = (const float*)d_in[10];

  char* ws = (char*)d_ws;
  const size_t SZP = (size_t)4096 * 1024 * 2;  // 8 MiB
  const size_t SZW = (size_t)1024 * 1024 * 2;  // 2 MiB
  bf16* Qb   = (bf16*)(ws + 0 * SZP);          // [BH][S][64] (prescaled)
  bf16* Kb   = (bf16*)(ws + 1 * SZP);          // [BH][S][64]
  bf16* Vt   = (bf16*)(ws + 2 * SZP);          // [BH][64][S] (rz-prescaled in place)
  bf16* ctxb = (bf16*)(ws + 3 * SZP);          // [B][S][D]
  bf16* qb16 = (bf16*)(ws + 4 * SZP);
  bf16* kb16 = (bf16*)(ws + 5 * SZP);
  bf16* vb16 = (bf16*)(ws + 6 * SZP);
  bf16* Wqb  = (bf16*)(ws + 7 * SZP + 0 * SZW);
  bf16* Wkb  = (bf16*)(ws + 7 * SZP + 1 * SZW);
  bf16* Wvb  = (bf16*)(ws + 7 * SZP + 2 * SZW);
  bf16* Wob  = (bf16*)(ws + 7 * SZP + 3 * SZW);
  float* zPart = (float*)(ws + 7 * SZP + 4 * SZW);     // [2][BH][SS] fp32
  float* cRZ   = zPart + (size_t)2 * BH * SS;          // [BH][SS] fp32
  float* vlastB = cRZ + (size_t)BH * SS;               // [BH][64] fp32

  cvt_w<<<dim3(512, 4), 256, 0, stream>>>(Wq, Wk, Wv, Wo, Wqb, Wkb, Wvb, Wob);
  cvt_x<<<dim3(2048, 3), 256, 0, stream>>>(q, k, v, qb16, kb16, vb16);

  proj_gemm<<<dim3(1024 / 128, 4096 / 128, 3), 256, 0, stream>>>(
      qb16, kb16, vb16, Wqb, Wkb, Wvb, bq, bk, bv, Qb, Kb, Vt);

  colz<<<1024, 256, 0, stream>>>(Qb, Kb, zPart);
  rzfin<<<(BH * SS / 4) / 256, 256, 0, stream>>>(zPart, cRZ);
  vscale<<<(BH * HD * SS / 8) / 256, 256, 0, stream>>>(Vt, cRZ, vlastB);
  attn_ctx<<<512, 512, 0, stream>>>(Qb, Kb, Vt, vlastB, ctxb);

  out_gemm<<<dim3(1024 / 128, 4096 / 128), 256, 0, stream>>>(ctxb, Wob, bo, (float*)d_out);
}

// Round 10
// 182.332 us; speedup vs baseline: 1.1277x; 1.1277x over previous
//
#include <hip/hip_runtime.h>

typedef __bf16 bf16;
typedef __attribute__((ext_vector_type(8))) __bf16 bf16x8;
typedef __attribute__((ext_vector_type(2))) __bf16 bf16x2;
typedef __attribute__((ext_vector_type(4))) float f32x4;

#define AS1 __attribute__((address_space(1)))
#define AS3 __attribute__((address_space(3)))

// Problem constants
#define BB 2
#define SS 2048
#define DD 1024
#define HH 16
#define HD 64
#define BH (BB*HH)

// 0.125 (1/sqrt(64)) * 1/ln(2): folded into Q so scores come out in log2 units
#define QSCALE 0.1803368801111244f

static __device__ __forceinline__ f32x4 mfma16(bf16x8 a, bf16x8 b, f32x4 c) {
  return __builtin_amdgcn_mfma_f32_16x16x32_bf16(a, b, c, 0, 0, 0);
}
static __device__ __forceinline__ float fexp2(float x) {
  return __builtin_amdgcn_exp2f(x);
}

// XCD-aware remap, 512-block grids: all 16 blocks of a bh on one XCD.
static __device__ __forceinline__ void swz512(int bid, int& bh, int& pr) {
  int c = bid & 7, j = bid >> 3;
  bh = c + 8 * (j & 3);
  pr = j >> 2;               // 0..15
}
// XCD-aware remap, 1024-block grids: all 32 blocks of a bh on one XCD.
static __device__ __forceinline__ void swz1024(int bid, int& bh, int& strip0, int& qh) {
  int c = bid & 7, j = bid >> 3;
  bh = c + 8 * (j & 3);
  int rem = j >> 2;          // 0..31
  strip0 = rem & 15;
  qh = rem >> 4;
}

// ---------------- fp32 -> bf16 conversion, fused (weights: 4 tensors) ----------------
__global__ __launch_bounds__(256) void cvt_w(const float* __restrict__ s0, const float* __restrict__ s1,
                                             const float* __restrict__ s2, const float* __restrict__ s3,
                                             bf16* __restrict__ o0, bf16* __restrict__ o1,
                                             bf16* __restrict__ o2, bf16* __restrict__ o3) {
  const int z = blockIdx.y;
  const float* s = (z == 0) ? s0 : (z == 1) ? s1 : (z == 2) ? s2 : s3;
  bf16* o = (z == 0) ? o0 : (z == 1) ? o1 : (z == 2) ? o2 : o3;
  int i = blockIdx.x * 256 + threadIdx.x;
  const float4* sp = (const float4*)s;
  float4 a = sp[2 * i], b = sp[2 * i + 1];
  bf16x8 v;
  v[0] = (bf16)a.x; v[1] = (bf16)a.y; v[2] = (bf16)a.z; v[3] = (bf16)a.w;
  v[4] = (bf16)b.x; v[5] = (bf16)b.y; v[6] = (bf16)b.z; v[7] = (bf16)b.w;
  ((bf16x8*)o)[i] = v;
}

// ---------------- fp32 -> bf16 conversion, fused (inputs: 3 tensors) ----------------
__global__ __launch_bounds__(256) void cvt_x(const float* __restrict__ s0, const float* __restrict__ s1,
                                             const float* __restrict__ s2,
                                             bf16* __restrict__ o0, bf16* __restrict__ o1,
                                             bf16* __restrict__ o2) {
  const int z = blockIdx.y;
  const float* s = (z == 0) ? s0 : (z == 1) ? s1 : s2;
  bf16* o = (z == 0) ? o0 : (z == 1) ? o1 : o2;
  int i = blockIdx.x * 256 + threadIdx.x;
  const float4* sp = (const float4*)s;
  float4 a = sp[2 * i], b = sp[2 * i + 1];
  bf16x8 v;
  v[0] = (bf16)a.x; v[1] = (bf16)a.y; v[2] = (bf16)a.z; v[3] = (bf16)a.w;
  v[4] = (bf16)b.x; v[5] = (bf16)b.y; v[6] = (bf16)b.z; v[7] = (bf16)b.w;
  ((bf16x8*)o)[i] = v;
}

// ---------------- core 128x128 bf16 NT GEMM (C = A * B^T), K mult of 32 ----------------
__device__ __forceinline__ void gemm_core(const bf16* __restrict__ A,
                                          const bf16* __restrict__ Bm, int K,
                                          int m0, int n0, int w, int l,
                                          bf16* sA, bf16* sB, f32x4 (&acc)[4][4]) {
  const int l15 = l & 15, lg = l >> 4;
  const int wr = (w >> 1) * 64, wc = (w & 1) * 64;
  for (int kt = 0; kt < K; kt += 32) {
#pragma unroll
    for (int i = 0; i < 2; ++i) {
      int t = i * 256 + w * 64 + l;
      const bf16* ga = A + (size_t)(m0 + (t >> 2)) * K + kt + (t & 3) * 8;
      const bf16* gb = Bm + (size_t)(n0 + (t >> 2)) * K + kt + (t & 3) * 8;
      __builtin_amdgcn_global_load_lds((const AS1 void*)ga,
                                       (AS3 void*)(sA + (i * 256 + w * 64) * 8), 16, 0, 0);
      __builtin_amdgcn_global_load_lds((const AS1 void*)gb,
                                       (AS3 void*)(sB + (i * 256 + w * 64) * 8), 16, 0, 0);
    }
    __syncthreads();
    bf16x8 af[4], bfr[4];
#pragma unroll
    for (int m = 0; m < 4; ++m)
      af[m] = *(const bf16x8*)(sA + (wr + m * 16 + l15) * 32 + lg * 8);
#pragma unroll
    for (int n = 0; n < 4; ++n)
      bfr[n] = *(const bf16x8*)(sB + (wc + n * 16 + l15) * 32 + lg * 8);
#pragma unroll
    for (int m = 0; m < 4; ++m)
#pragma unroll
      for (int n = 0; n < 4; ++n)
        acc[m][n] = mfma16(af[m], bfr[n], acc[m][n]);
    __syncthreads();
  }
}

// ---------------- batched QKV projection: y = x @ W^T + b, heads layout ----------------
// z=0: Q (prescaled by QSCALE) -> [BH][S][64]; z=1: K -> [BH][S][64]; z=2: V -> [BH][64][S]
__global__ __launch_bounds__(256) void proj_gemm(
    const bf16* __restrict__ Xq, const bf16* __restrict__ Xk, const bf16* __restrict__ Xv,
    const bf16* __restrict__ Wq, const bf16* __restrict__ Wk, const bf16* __restrict__ Wv,
    const float* __restrict__ bq, const float* __restrict__ bk, const float* __restrict__ bv,
    bf16* __restrict__ Oq, bf16* __restrict__ Ok, bf16* __restrict__ Ovt) {
  __shared__ __align__(16) bf16 sA[128 * 32];
  __shared__ __align__(16) bf16 sB[128 * 32];
  const int z = blockIdx.z;
  const bf16* A = (z == 0) ? Xq : ((z == 1) ? Xk : Xv);
  const bf16* W = (z == 0) ? Wq : ((z == 1) ? Wk : Wv);
  const float* bias = (z == 0) ? bq : ((z == 1) ? bk : bv);
  const int tid = threadIdx.x, l = tid & 63, w = tid >> 6;
  const int m0 = blockIdx.y * 128, n0 = blockIdx.x * 128;
  f32x4 acc[4][4] = {};
  gemm_core(A, W, DD, m0, n0, w, l, sA, sB, acc);
  const int l15 = l & 15, lg = l >> 4;
  const int wr = (w >> 1) * 64, wc = (w & 1) * 64;
#pragma unroll
  for (int n = 0; n < 4; ++n) {
    int col = n0 + wc + n * 16 + l15;
    float bb = bias[col];
    int h = col >> 6, d = col & 63;
#pragma unroll
    for (int m = 0; m < 4; ++m) {
#pragma unroll
      for (int r = 0; r < 4; ++r) {
        int row = m0 + wr + m * 16 + lg * 4 + r;
        int b = row >> 11, s = row & (SS - 1);
        float vv = acc[m][n][r] + bb;
        if (z == 0) vv *= QSCALE;
        if (z != 2)
          ((z == 0) ? Oq : Ok)[(((size_t)(b * HH + h)) * SS + s) * HD + d] = (bf16)vv;
        else
          Ovt[(((size_t)(b * HH + h)) * HD + d) * SS + s] = (bf16)vv;
      }
    }
  }
}

// ---------------- output projection: out = ctx @ Wo^T + bo (fp32 out) ----------------
__global__ __launch_bounds__(256) void out_gemm(const bf16* __restrict__ A,
                                                const bf16* __restrict__ W,
                                                const float* __restrict__ bias,
                                                float* __restrict__ out) {
  __shared__ __align__(16) bf16 sA[128 * 32];
  __shared__ __align__(16) bf16 sB[128 * 32];
  const int tid = threadIdx.x, l = tid & 63, w = tid >> 6;
  const int m0 = blockIdx.y * 128, n0 = blockIdx.x * 128;
  f32x4 acc[4][4] = {};
  gemm_core(A, W, DD, m0, n0, w, l, sA, sB, acc);
  const int l15 = l & 15, lg = l >> 4;
  const int wr = (w >> 1) * 64, wc = (w & 1) * 64;
#pragma unroll
  for (int n = 0; n < 4; ++n) {
    int col = n0 + wc + n * 16 + l15;
    float bb = bias[col];
#pragma unroll
    for (int m = 0; m < 4; ++m)
#pragma unroll
      for (int r = 0; r < 4; ++r) {
        int row = m0 + wr + m * 16 + lg * 4 + r;
        out[(size_t)row * DD + col] = acc[m][n][r] + bb;
      }
  }
}

// ---------------- pass A: per-column partial softmax denominator -----------------------
__global__ __launch_bounds__(256) void colz(const bf16* __restrict__ Qb,
                                            const bf16* __restrict__ Kb,
                                            float* __restrict__ zPart) {
  __shared__ float zred[4][64];
  int bh, pair, qh;
  swz1024(blockIdx.x, bh, pair, qh);
  const int tid = threadIdx.x, l = tid & 63, w = tid >> 6;
  const int l15 = l & 15, lg = l >> 4;
  const bf16* Q = Qb + (size_t)bh * SS * HD;
  const bf16* Kh = Kb + (size_t)bh * SS * HD;

  for (int half = 0; half < 2; ++half) {
    const int s = half ? (31 - pair) : pair;
    const int c0 = s * 64;
    bf16x8 kf[4][2];
#pragma unroll
    for (int kt = 0; kt < 4; ++kt) {
      kf[kt][0] = *(const bf16x8*)&Kh[(c0 + kt * 16 + l15) * HD + lg * 8];
      kf[kt][1] = *(const bf16x8*)&Kh[(c0 + kt * 16 + l15) * HD + 32 + lg * 8];
    }
    float z[4] = {};
    const int qstart = c0 + qh * 64 + w * 16;
    bf16x8 qa0, qa1, qn0, qn1;
    if (qstart < SS) {
      qa0 = *(const bf16x8*)&Q[(qstart + l15) * HD + lg * 8];
      qa1 = *(const bf16x8*)&Q[(qstart + l15) * HD + 32 + lg * 8];
    }
    for (int qb = qstart; qb < SS; qb += 128) {
      const int qnext = qb + 128;
      if (qnext < SS) {
        qn0 = *(const bf16x8*)&Q[(qnext + l15) * HD + lg * 8];
        qn1 = *(const bf16x8*)&Q[(qnext + l15) * HD + 32 + lg * 8];
      }
      f32x4 d[4] = {};
#pragma unroll
      for (int kt = 0; kt < 4; ++kt) {
        d[kt] = mfma16(qa0, kf[kt][0], d[kt]);
        d[kt] = mfma16(qa1, kf[kt][1], d[kt]);
      }
#pragma unroll
      for (int kt = 0; kt < 4; ++kt) {
        const int kcol = c0 + kt * 16 + l15;
#pragma unroll
        for (int r = 0; r < 4; ++r) {
          int qq = qb + lg * 4 + r;
          z[kt] += (qq > kcol) ? fexp2(d[kt][r]) : 0.f;
        }
      }
      qa0 = qn0; qa1 = qn1;
    }
#pragma unroll
    for (int kt = 0; kt < 4; ++kt) {
      z[kt] += __shfl_xor(z[kt], 16);
      z[kt] += __shfl_xor(z[kt], 32);
    }
    if (l < 16) {
#pragma unroll
      for (int kt = 0; kt < 4; ++kt) zred[w][kt * 16 + l15] = z[kt];
    }
    __syncthreads();
    if (tid < 64) {
      float zs = zred[0][tid] + zred[1][tid] + zred[2][tid] + zred[3][tid];
      zPart[((size_t)qh * BH + bh) * SS + c0 + tid] = zs;
    }
    __syncthreads();
  }
}

// ---------------- combine the two z partials into reciprocal denominators --------------
__global__ __launch_bounds__(256) void rzfin(const float* __restrict__ zPart,
                                             float* __restrict__ cRZ) {
  int i = blockIdx.x * 256 + threadIdx.x;  // f32x4 index over BH*SS
  f32x4 a = ((const f32x4*)zPart)[i];
  f32x4 b = ((const f32x4*)(zPart + (size_t)BH * SS))[i];
  f32x4 r;
#pragma unroll
  for (int j = 0; j < 4; ++j) {
    float s = a[j] + b[j];
    r[j] = (s > 0.f) ? 1.0f / s : 0.f;
  }
  ((f32x4*)cRZ)[i] = r;
}

// ---------------- prescale V columns by rz (in place); save vlast column first ----------
__global__ __launch_bounds__(256) void vscale(bf16* __restrict__ Vt,
                                              const float* __restrict__ cRZ,
                                              float* __restrict__ vlastB) {
  int i = blockIdx.x * 256 + threadIdx.x;  // (bh*64+d) * 256 s-chunks
  int sc = i & (SS / 8 - 1);
  int rest = i >> 8;                       // bh*64 + d
  int s0 = sc * 8;
  bf16* p = Vt + (size_t)rest * SS + s0;
  const float* rz = cRZ + (size_t)(rest >> 6) * SS + s0;
  bf16x8 v = *(const bf16x8*)p;
  if (s0 + 8 == SS) vlastB[rest] = (float)v[7] * (1.0f / (float)SS);
  f32x4 r0 = *(const f32x4*)rz, r1 = *(const f32x4*)(rz + 4);
  bf16x8 o;
#pragma unroll
  for (int j = 0; j < 4; ++j) o[j] = (bf16)((float)v[j] * r0[j]);
#pragma unroll
  for (int j = 0; j < 4; ++j) o[4 + j] = (bf16)((float)v[4 + j] * r1[j]);
  *(bf16x8*)p = o;
}

// ---------------- pass B building blocks ------------------------------------------------
// KV register buffer for one 32-k chunk: 4 K fragments + 4 pi-permuted V' fragments.
struct KV {
  bf16x8 k[4];
  unsigned int v[4][4];
};

static __device__ __forceinline__ void kv_load(KV& b, const bf16* __restrict__ Kh,
                                               const bf16* __restrict__ V, int k0,
                                               int l15, int lg) {
  b.k[0] = *(const bf16x8*)&Kh[(k0 + l15) * HD + lg * 8];
  b.k[1] = *(const bf16x8*)&Kh[(k0 + l15) * HD + 32 + lg * 8];
  b.k[2] = *(const bf16x8*)&Kh[(k0 + 16 + l15) * HD + lg * 8];
  b.k[3] = *(const bf16x8*)&Kh[(k0 + 16 + l15) * HD + 32 + lg * 8];
#pragma unroll
  for (int dt = 0; dt < 4; ++dt) {
    const bf16* vrow = &V[(size_t)(dt * 16 + l15) * SS];
    uint2 lo = *(const uint2*)&vrow[k0 + 4 * lg];
    uint2 hi = *(const uint2*)&vrow[k0 + 16 + 4 * lg];
    b.v[dt][0] = lo.x; b.v[dt][1] = lo.y; b.v[dt][2] = hi.x; b.v[dt][3] = hi.y;
  }
}

// Swapped QK^T (mfma(K,Q)) -> lane holds P[q=l15][k]; packed lane-locally into the PV
// A-fragment under pi(8lg+j) = (j<4 ? 4lg+j : 16+4lg+j-4); V' fragments use the same pi.
// DIAG=false chunks (k0+32 <= q0) are provably fully unmasked -> no compare/select.
template <bool DIAG>
static __device__ __forceinline__ void kv_compute(const KV& b, int k0, int q0,
                                                  const bf16x8 (&qa)[4][2],
                                                  f32x4 (&acc)[4][4], int l15, int lg) {
  const int kb0i = k0 + lg * 4, kb1i = k0 + 16 + lg * 4;
#pragma unroll
  for (int qt = 0; qt < 4; ++qt) {
    f32x4 s0 = {}, s1 = {};
    s0 = mfma16(b.k[0], qa[qt][0], s0);
    s0 = mfma16(b.k[1], qa[qt][1], s0);
    s1 = mfma16(b.k[2], qa[qt][0], s1);
    s1 = mfma16(b.k[3], qa[qt][1], s1);
    const int qq = q0 + qt * 16 + l15;
    union { unsigned int u[4]; bf16x8 v; } pa;
#pragma unroll
    for (int hw = 0; hw < 2; ++hw) {
      bf16x2 t0, t1;
#pragma unroll
      for (int r = 0; r < 2; ++r) {
        int rr = hw * 2 + r;
        float p0 = fexp2(s0[rr]);
        float p1 = fexp2(s1[rr]);
        if (DIAG) {
          p0 = (kb0i + rr < qq) ? p0 : 0.f;
          p1 = (kb1i + rr < qq) ? p1 : 0.f;
        }
        t0[r] = (bf16)p0;
        t1[r] = (bf16)p1;
      }
      pa.u[hw] = __builtin_bit_cast(unsigned int, t0);
      pa.u[hw + 2] = __builtin_bit_cast(unsigned int, t1);
    }
#pragma unroll
    for (int dt = 0; dt < 4; ++dt) {
      union { unsigned int u[4]; bf16x8 v; } vf;
      vf.u[0] = b.v[dt][0]; vf.u[1] = b.v[dt][1];
      vf.u[2] = b.v[dt][2]; vf.u[3] = b.v[dt][3];
      acc[qt][dt] = mfma16(pa.v, vf.v, acc[qt][dt]);
    }
  }
}

// ---------------- pass B: 64q tiles paired (t, 31-t); k-split 8 ways across
// (2 blocks per pair) x (4 waves). Grid 1024, 256-thread blocks, VGPR-safe (256,2).
// ~8-9 serial chunks per wave. Block kh writes a bf16 PARTIAL ctx (ctxP0 / ctxP1);
// ctxfin adds them + vlast. 2-buffer LDS merge tree (35 KB).
__global__ __launch_bounds__(256, 2) void attn_ctx(const bf16* __restrict__ Qb,
                                                   const bf16* __restrict__ Kb,
                                                   const bf16* __restrict__ Vt,
                                                   bf16* __restrict__ ctxP0,
                                                   bf16* __restrict__ ctxP1) {
  __shared__ __align__(16) float red[2][64 * 68];  // [d][q] pitch 68 (34.8 KB)
  int bh, pr, kh;
  swz1024(blockIdx.x, bh, pr, kh);
  const int tid = threadIdx.x, l = tid & 63, w = tid >> 6;
  const int l15 = l & 15, lg = l >> 4;
  const int s = kh * 4 + w;  // k-slot 0..7
  const bf16* Q = Qb + (size_t)bh * SS * HD;
  const bf16* Kh = Kb + (size_t)bh * SS * HD;
  const bf16* V = Vt + (size_t)bh * HD * SS;  // [64][S], rz-prescaled
  bf16* ctxP = kh ? ctxP1 : ctxP0;
  const int b = bh >> 4, h = bh & 15;

  for (int half = 0; half < 2; ++half) {
    const int t = half ? (31 - pr) : pr;
    const int q0 = t * 64;

    bf16x8 qa[4][2];
#pragma unroll
    for (int qt = 0; qt < 4; ++qt)
#pragma unroll
      for (int kk = 0; kk < 2; ++kk)
        qa[qt][kk] = *(const bf16x8*)&Q[(q0 + qt * 16 + l15) * HD + kk * 32 + lg * 8];

    f32x4 acc[4][4] = {};  // [qt][dt]
    KV A;
    // unmasked chunks: k0 = s*32 + 256j < q0
    for (int k0 = s * 32; k0 < q0; k0 += 256) {
      kv_load(A, Kh, V, k0, l15, lg);
      kv_compute<false>(A, k0, q0, qa, acc, l15, lg);
    }
    // diagonal chunks k0 = q0, q0+32 -> slots (2t)&7 and (2t+1)&7
    {
      const int cw = (2 * t) & 7;
      int dk = (s == cw) ? q0 : ((s == ((cw + 1) & 7)) ? q0 + 32 : -1);
      if (dk >= 0) {
        kv_load(A, Kh, V, dk, l15, lg);
        kv_compute<true>(A, dk, q0, qa, acc, l15, lg);
      }
    }

    // merge 4 per-wave partials with 2 buffers: w1->bufA, w3->bufB; w0+=A, w2+=B;
    // then w2->bufA; w0+=A; w0 writes the block's partial ctx.
    if (w == 1 || w == 3) {
      float* buf = red[(w - 1) >> 1];
#pragma unroll
      for (int qt = 0; qt < 4; ++qt)
#pragma unroll
        for (int dt = 0; dt < 4; ++dt)
          *(f32x4*)&buf[(dt * 16 + l15) * 68 + qt * 16 + lg * 4] = acc[qt][dt];
    }
    __syncthreads();
    if (w == 0 || w == 2) {
      const float* buf = red[w >> 1];
#pragma unroll
      for (int qt = 0; qt < 4; ++qt)
#pragma unroll
        for (int dt = 0; dt < 4; ++dt)
          acc[qt][dt] += *(const f32x4*)&buf[(dt * 16 + l15) * 68 + qt * 16 + lg * 4];
    }
    __syncthreads();
    if (w == 2) {
#pragma unroll
      for (int qt = 0; qt < 4; ++qt)
#pragma unroll
        for (int dt = 0; dt < 4; ++dt)
          *(f32x4*)&red[0][(dt * 16 + l15) * 68 + qt * 16 + lg * 4] = acc[qt][dt];
    }
    __syncthreads();
    if (w == 0) {
#pragma unroll
      for (int qt = 0; qt < 4; ++qt) {
#pragma unroll
        for (int dt = 0; dt < 4; ++dt) {
          f32x4 a = acc[qt][dt];
          a += *(const f32x4*)&red[0][(dt * 16 + l15) * 68 + qt * 16 + lg * 4];
#pragma unroll
          for (int r = 0; r < 4; ++r) {
            int q = q0 + qt * 16 + lg * 4 + r;
            ctxP[((size_t)(b * SS + q)) * DD + h * HD + dt * 16 + l15] = (bf16)a[r];
          }
        }
      }
    }
    __syncthreads();  // protect red before next half reuses it
  }
}

// ---------------- combine partial ctx halves + vlast -> final bf16 ctx (in place on P0) -
__global__ __launch_bounds__(256) void ctxfin(const bf16* __restrict__ P1,
                                              const float* __restrict__ vlastB,
                                              bf16* __restrict__ ctx) {
  int i = blockIdx.x * 256 + threadIdx.x;  // bf16x8 index over [4096][1024]
  int e0 = i * 8;
  int row = e0 >> 10, col = e0 & (DD - 1);
  int b = row >> 11;
  int vidx = (b * HH + (col >> 6)) * 64 + (col & 63);
  bf16x8 p0 = ((const bf16x8*)ctx)[i];
  bf16x8 p1 = ((const bf16x8*)P1)[i];
  f32x4 v0 = *(const f32x4*)&vlastB[vidx];
  f32x4 v1 = *(const f32x4*)&vlastB[vidx + 4];
  bf16x8 o;
#pragma unroll
  for (int j = 0; j < 4; ++j) o[j] = (bf16)((float)p0[j] + (float)p1[j] + v0[j]);
#pragma unroll
  for (int j = 0; j < 4; ++j) o[4 + j] = (bf16)((float)p0[4 + j] + (float)p1[4 + j] + v1[j]);
  ((bf16x8*)ctx)[i] = o;
}

// ---------------- launcher ----------------
extern "C" void kernel_launch(void* const* d_in, const int* in_sizes, int n_in,
                              void* d_out, int out_size, void* d_ws, size_t ws_size,
                              hipStream_t stream) {
  const float* q  = (const float*)d_in[0];
  const float* k  = (const float*)d_in[1];
  const float* v  = (const float*)d_in[2];
  const float* Wq = (const float*)d_in[3];
  const float* bq = (const float*)d_in[4];
  const float* Wk = (const float*)d_in[5];
  const float* bk = (const float*)d_in[6];
  const float* Wv = (const float*)d_in[7];
  const float* bv = (const float*)d_in[8];
  const float* Wo = (const float*)d_in[9];
  const float* bo = (const float*)d_in[10];

  char* ws = (char*)d_ws;
  const size_t SZP = (size_t)4096 * 1024 * 2;  // 8 MiB
  const size_t SZW = (size_t)1024 * 1024 * 2;  // 2 MiB
  bf16* Qb   = (bf16*)(ws + 0 * SZP);          // [BH][S][64] (prescaled)
  bf16* Kb   = (bf16*)(ws + 1 * SZP);          // [BH][S][64]
  bf16* Vt   = (bf16*)(ws + 2 * SZP);          // [BH][64][S] (rz-prescaled in place)
  bf16* ctxb = (bf16*)(ws + 3 * SZP);          // [B][S][D]; also ctx partial 0
  bf16* qb16 = (bf16*)(ws + 4 * SZP);          // dead after proj_gemm -> ctx partial 1
  bf16* kb16 = (bf16*)(ws + 5 * SZP);
  bf16* vb16 = (bf16*)(ws + 6 * SZP);
  bf16* Wqb  = (bf16*)(ws + 7 * SZP + 0 * SZW);
  bf16* Wkb  = (bf16*)(ws + 7 * SZP + 1 * SZW);
  bf16* Wvb  = (bf16*)(ws + 7 * SZP + 2 * SZW);
  bf16* Wob  = (bf16*)(ws + 7 * SZP + 3 * SZW);
  float* zPart = (float*)(ws + 7 * SZP + 4 * SZW);     // [2][BH][SS] fp32
  float* cRZ   = zPart + (size_t)2 * BH * SS;          // [BH][SS] fp32
  float* vlastB = cRZ + (size_t)BH * SS;               // [BH][64] fp32
  bf16* ctxP1 = qb16;                                  // reuse input-x bf16 region

  cvt_w<<<dim3(512, 4), 256, 0, stream>>>(Wq, Wk, Wv, Wo, Wqb, Wkb, Wvb, Wob);
  cvt_x<<<dim3(2048, 3), 256, 0, stream>>>(q, k, v, qb16, kb16, vb16);

  proj_gemm<<<dim3(1024 / 128, 4096 / 128, 3), 256, 0, stream>>>(
      qb16, kb16, vb16, Wqb, Wkb, Wvb, bq, bk, bv, Qb, Kb, Vt);

  colz<<<1024, 256, 0, stream>>>(Qb, Kb, zPart);
  rzfin<<<(BH * SS / 4) / 256, 256, 0, stream>>>(zPart, cRZ);
  vscale<<<(BH * HD * SS / 8) / 256, 256, 0, stream>>>(Vt, cRZ, vlastB);
  attn_ctx<<<1024, 256, 0, stream>>>(Qb, Kb, Vt, ctxb, ctxP1);
  ctxfin<<<(4096 * 1024 / 8) / 256, 256, 0, stream>>>(ctxP1, vlastB, ctxb);

  out_gemm<<<dim3(1024 / 128, 4096 / 128), 256, 0, stream>>>(ctxb, Wob, bo, (float*)d_out);
}

// Round 11
// 168.152 us; speedup vs baseline: 1.2228x; 1.0843x over previous
//
#include <hip/hip_runtime.h>

typedef __bf16 bf16;
typedef __attribute__((ext_vector_type(8))) __bf16 bf16x8;
typedef __attribute__((ext_vector_type(2))) __bf16 bf16x2;
typedef __attribute__((ext_vector_type(4))) float f32x4;

#define AS1 __attribute__((address_space(1)))
#define AS3 __attribute__((address_space(3)))

// Problem constants
#define BB 2
#define SS 2048
#define DD 1024
#define HH 16
#define HD 64
#define BH (BB*HH)

// 0.125 (1/sqrt(64)) * 1/ln(2): folded into Q so scores come out in log2 units
#define QSCALE 0.1803368801111244f

static __device__ __forceinline__ f32x4 mfma16(bf16x8 a, bf16x8 b, f32x4 c) {
  return __builtin_amdgcn_mfma_f32_16x16x32_bf16(a, b, c, 0, 0, 0);
}
static __device__ __forceinline__ float fexp2(float x) {
  return __builtin_amdgcn_exp2f(x);
}

// XCD-aware remap, 1024-block grids: all 32 blocks of a bh on one XCD.
static __device__ __forceinline__ void swz1024(int bid, int& bh, int& strip0, int& qh) {
  int c = bid & 7, j = bid >> 3;
  bh = c + 8 * (j & 3);
  int rem = j >> 2;          // 0..31
  strip0 = rem & 15;
  qh = rem >> 4;
}

// ---------------- fp32 -> bf16 conversion, fused (weights: 4 tensors) ----------------
__global__ __launch_bounds__(256) void cvt_w(const float* __restrict__ s0, const float* __restrict__ s1,
                                             const float* __restrict__ s2, const float* __restrict__ s3,
                                             bf16* __restrict__ o0, bf16* __restrict__ o1,
                                             bf16* __restrict__ o2, bf16* __restrict__ o3) {
  const int z = blockIdx.y;
  const float* s = (z == 0) ? s0 : (z == 1) ? s1 : (z == 2) ? s2 : s3;
  bf16* o = (z == 0) ? o0 : (z == 1) ? o1 : (z == 2) ? o2 : o3;
  int i = blockIdx.x * 256 + threadIdx.x;
  const float4* sp = (const float4*)s;
  float4 a = sp[2 * i], b = sp[2 * i + 1];
  bf16x8 v;
  v[0] = (bf16)a.x; v[1] = (bf16)a.y; v[2] = (bf16)a.z; v[3] = (bf16)a.w;
  v[4] = (bf16)b.x; v[5] = (bf16)b.y; v[6] = (bf16)b.z; v[7] = (bf16)b.w;
  ((bf16x8*)o)[i] = v;
}

// ---------------- fp32 -> bf16 conversion, fused (inputs: 3 tensors) ----------------
__global__ __launch_bounds__(256) void cvt_x(const float* __restrict__ s0, const float* __restrict__ s1,
                                             const float* __restrict__ s2,
                                             bf16* __restrict__ o0, bf16* __restrict__ o1,
                                             bf16* __restrict__ o2) {
  const int z = blockIdx.y;
  const float* s = (z == 0) ? s0 : (z == 1) ? s1 : s2;
  bf16* o = (z == 0) ? o0 : (z == 1) ? o1 : o2;
  int i = blockIdx.x * 256 + threadIdx.x;
  const float4* sp = (const float4*)s;
  float4 a = sp[2 * i], b = sp[2 * i + 1];
  bf16x8 v;
  v[0] = (bf16)a.x; v[1] = (bf16)a.y; v[2] = (bf16)a.z; v[3] = (bf16)a.w;
  v[4] = (bf16)b.x; v[5] = (bf16)b.y; v[6] = (bf16)b.z; v[7] = (bf16)b.w;
  ((bf16x8*)o)[i] = v;
}

// ---------------- core 128x128 bf16 NT GEMM (C = A * B^T), K mult of 32 ----------------
__device__ __forceinline__ void gemm_core(const bf16* __restrict__ A,
                                          const bf16* __restrict__ Bm, int K,
                                          int m0, int n0, int w, int l,
                                          bf16* sA, bf16* sB, f32x4 (&acc)[4][4]) {
  const int l15 = l & 15, lg = l >> 4;
  const int wr = (w >> 1) * 64, wc = (w & 1) * 64;
  for (int kt = 0; kt < K; kt += 32) {
#pragma unroll
    for (int i = 0; i < 2; ++i) {
      int t = i * 256 + w * 64 + l;
      const bf16* ga = A + (size_t)(m0 + (t >> 2)) * K + kt + (t & 3) * 8;
      const bf16* gb = Bm + (size_t)(n0 + (t >> 2)) * K + kt + (t & 3) * 8;
      __builtin_amdgcn_global_load_lds((const AS1 void*)ga,
                                       (AS3 void*)(sA + (i * 256 + w * 64) * 8), 16, 0, 0);
      __builtin_amdgcn_global_load_lds((const AS1 void*)gb,
                                       (AS3 void*)(sB + (i * 256 + w * 64) * 8), 16, 0, 0);
    }
    __syncthreads();
    bf16x8 af[4], bfr[4];
#pragma unroll
    for (int m = 0; m < 4; ++m)
      af[m] = *(const bf16x8*)(sA + (wr + m * 16 + l15) * 32 + lg * 8);
#pragma unroll
    for (int n = 0; n < 4; ++n)
      bfr[n] = *(const bf16x8*)(sB + (wc + n * 16 + l15) * 32 + lg * 8);
#pragma unroll
    for (int m = 0; m < 4; ++m)
#pragma unroll
      for (int n = 0; n < 4; ++n)
        acc[m][n] = mfma16(af[m], bfr[n], acc[m][n]);
    __syncthreads();
  }
}

// ---------------- batched QKV projection: y = x @ W^T + b, heads layout ----------------
// z=0: Q (prescaled by QSCALE) -> [BH][S][64]; z=1: K -> [BH][S][64]
// z=2: V -> TILE-MAJOR [BH][S/32][64][32]  (each 32-k tile contiguous 4KB)
__global__ __launch_bounds__(256) void proj_gemm(
    const bf16* __restrict__ Xq, const bf16* __restrict__ Xk, const bf16* __restrict__ Xv,
    const bf16* __restrict__ Wq, const bf16* __restrict__ Wk, const bf16* __restrict__ Wv,
    const float* __restrict__ bq, const float* __restrict__ bk, const float* __restrict__ bv,
    bf16* __restrict__ Oq, bf16* __restrict__ Ok, bf16* __restrict__ Ovt) {
  __shared__ __align__(16) bf16 sA[128 * 32];
  __shared__ __align__(16) bf16 sB[128 * 32];
  const int z = blockIdx.z;
  const bf16* A = (z == 0) ? Xq : ((z == 1) ? Xk : Xv);
  const bf16* W = (z == 0) ? Wq : ((z == 1) ? Wk : Wv);
  const float* bias = (z == 0) ? bq : ((z == 1) ? bk : bv);
  const int tid = threadIdx.x, l = tid & 63, w = tid >> 6;
  const int m0 = blockIdx.y * 128, n0 = blockIdx.x * 128;
  f32x4 acc[4][4] = {};
  gemm_core(A, W, DD, m0, n0, w, l, sA, sB, acc);
  const int l15 = l & 15, lg = l >> 4;
  const int wr = (w >> 1) * 64, wc = (w & 1) * 64;
#pragma unroll
  for (int n = 0; n < 4; ++n) {
    int col = n0 + wc + n * 16 + l15;
    float bb = bias[col];
    int h = col >> 6, d = col & 63;
#pragma unroll
    for (int m = 0; m < 4; ++m) {
#pragma unroll
      for (int r = 0; r < 4; ++r) {
        int row = m0 + wr + m * 16 + lg * 4 + r;
        int b = row >> 11, s = row & (SS - 1);
        float vv = acc[m][n][r] + bb;
        if (z == 0) vv *= QSCALE;
        if (z != 2)
          ((z == 0) ? Oq : Ok)[(((size_t)(b * HH + h)) * SS + s) * HD + d] = (bf16)vv;
        else
          Ovt[(size_t)(b * HH + h) * SS * HD + ((s >> 5) * 64 + d) * 32 + (s & 31)] = (bf16)vv;
      }
    }
  }
}

// ---------------- output projection: out = ctx @ Wo^T + bo (fp32 out) ----------------
__global__ __launch_bounds__(256) void out_gemm(const bf16* __restrict__ A,
                                                const bf16* __restrict__ W,
                                                const float* __restrict__ bias,
                                                float* __restrict__ out) {
  __shared__ __align__(16) bf16 sA[128 * 32];
  __shared__ __align__(16) bf16 sB[128 * 32];
  const int tid = threadIdx.x, l = tid & 63, w = tid >> 6;
  const int m0 = blockIdx.y * 128, n0 = blockIdx.x * 128;
  f32x4 acc[4][4] = {};
  gemm_core(A, W, DD, m0, n0, w, l, sA, sB, acc);
  const int l15 = l & 15, lg = l >> 4;
  const int wr = (w >> 1) * 64, wc = (w & 1) * 64;
#pragma unroll
  for (int n = 0; n < 4; ++n) {
    int col = n0 + wc + n * 16 + l15;
    float bb = bias[col];
#pragma unroll
    for (int m = 0; m < 4; ++m)
#pragma unroll
      for (int r = 0; r < 4; ++r) {
        int row = m0 + wr + m * 16 + lg * 4 + r;
        out[(size_t)row * DD + col] = acc[m][n][r] + bb;
      }
  }
}

// ---------------- pass A: per-column partial softmax denominator -----------------------
__global__ __launch_bounds__(256) void colz(const bf16* __restrict__ Qb,
                                            const bf16* __restrict__ Kb,
                                            float* __restrict__ zPart) {
  __shared__ float zred[4][64];
  int bh, pair, qh;
  swz1024(blockIdx.x, bh, pair, qh);
  const int tid = threadIdx.x, l = tid & 63, w = tid >> 6;
  const int l15 = l & 15, lg = l >> 4;
  const bf16* Q = Qb + (size_t)bh * SS * HD;
  const bf16* Kh = Kb + (size_t)bh * SS * HD;

  for (int half = 0; half < 2; ++half) {
    const int s = half ? (31 - pair) : pair;
    const int c0 = s * 64;
    bf16x8 kf[4][2];
#pragma unroll
    for (int kt = 0; kt < 4; ++kt) {
      kf[kt][0] = *(const bf16x8*)&Kh[(c0 + kt * 16 + l15) * HD + lg * 8];
      kf[kt][1] = *(const bf16x8*)&Kh[(c0 + kt * 16 + l15) * HD + 32 + lg * 8];
    }
    float z[4] = {};
    const int qstart = c0 + qh * 64 + w * 16;
    bf16x8 qa0, qa1, qn0, qn1;
    if (qstart < SS) {
      qa0 = *(const bf16x8*)&Q[(qstart + l15) * HD + lg * 8];
      qa1 = *(const bf16x8*)&Q[(qstart + l15) * HD + 32 + lg * 8];
    }
    for (int qb = qstart; qb < SS; qb += 128) {
      const int qnext = qb + 128;
      if (qnext < SS) {
        qn0 = *(const bf16x8*)&Q[(qnext + l15) * HD + lg * 8];
        qn1 = *(const bf16x8*)&Q[(qnext + l15) * HD + 32 + lg * 8];
      }
      f32x4 d[4] = {};
#pragma unroll
      for (int kt = 0; kt < 4; ++kt) {
        d[kt] = mfma16(qa0, kf[kt][0], d[kt]);
        d[kt] = mfma16(qa1, kf[kt][1], d[kt]);
      }
#pragma unroll
      for (int kt = 0; kt < 4; ++kt) {
        const int kcol = c0 + kt * 16 + l15;
#pragma unroll
        for (int r = 0; r < 4; ++r) {
          int qq = qb + lg * 4 + r;
          z[kt] += (qq > kcol) ? fexp2(d[kt][r]) : 0.f;
        }
      }
      qa0 = qn0; qa1 = qn1;
    }
#pragma unroll
    for (int kt = 0; kt < 4; ++kt) {
      z[kt] += __shfl_xor(z[kt], 16);
      z[kt] += __shfl_xor(z[kt], 32);
    }
    if (l < 16) {
#pragma unroll
      for (int kt = 0; kt < 4; ++kt) zred[w][kt * 16 + l15] = z[kt];
    }
    __syncthreads();
    if (tid < 64) {
      float zs = zred[0][tid] + zred[1][tid] + zred[2][tid] + zred[3][tid];
      zPart[((size_t)qh * BH + bh) * SS + c0 + tid] = zs;
    }
    __syncthreads();
  }
}

// ---------------- combine the two z partials into reciprocal denominators --------------
__global__ __launch_bounds__(256) void rzfin(const float* __restrict__ zPart,
                                             float* __restrict__ cRZ) {
  int i = blockIdx.x * 256 + threadIdx.x;  // f32x4 index over BH*SS
  f32x4 a = ((const f32x4*)zPart)[i];
  f32x4 b = ((const f32x4*)(zPart + (size_t)BH * SS))[i];
  f32x4 r;
#pragma unroll
  for (int j = 0; j < 4; ++j) {
    float s = a[j] + b[j];
    r[j] = (s > 0.f) ? 1.0f / s : 0.f;
  }
  ((f32x4*)cRZ)[i] = r;
}

// ---------------- prescale tile-major V by rz (in place); save vlast column first -------
// Vt [BH][64][64][32]: V'[bh][ts][d][ks] *= rz[bh][ts*32+ks]. Element s=S-1 (ts=63,ks=31)
// saved (pre-scale) as the uniform 1/S contribution to vlastB[bh*64+d].
__global__ __launch_bounds__(256) void vscale(bf16* __restrict__ Vt,
                                              const float* __restrict__ cRZ,
                                              float* __restrict__ vlastB) {
  int i = blockIdx.x * 256 + threadIdx.x;  // bf16x8 index over BH*64*64*4
  int ks8 = i & 3;
  int d = (i >> 2) & 63;
  int ts = (i >> 8) & 63;
  int bh = i >> 14;
  bf16* p = Vt + ((((size_t)bh * 64 + ts) * 64 + d) * 32) + ks8 * 8;
  const float* rz = cRZ + (size_t)bh * SS + ts * 32 + ks8 * 8;
  bf16x8 v = *(const bf16x8*)p;
  if (ts == 63 && ks8 == 3) vlastB[bh * 64 + d] = (float)v[7] * (1.0f / (float)SS);
  f32x4 r0 = *(const f32x4*)rz, r1 = *(const f32x4*)(rz + 4);
  bf16x8 o;
#pragma unroll
  for (int j = 0; j < 4; ++j) o[j] = (bf16)((float)v[j] * r0[j]);
#pragma unroll
  for (int j = 0; j < 4; ++j) o[4 + j] = (bf16)((float)v[4 + j] * r1[j]);
  *(bf16x8*)p = o;
}

// ---------------- pass B building blocks ------------------------------------------------
// KV register buffer for one 32-k chunk: 4 K fragments + 4 pi-permuted V' fragments.
// V is tile-major: the chunk's V tile is a CONTIGUOUS 4KB block -> dense fragment loads.
struct KV {
  bf16x8 k[4];
  unsigned int v[4][4];
};

static __device__ __forceinline__ void kv_load(KV& b, const bf16* __restrict__ Kh,
                                               const bf16* __restrict__ V, int k0,
                                               int l15, int lg) {
  b.k[0] = *(const bf16x8*)&Kh[(k0 + l15) * HD + lg * 8];
  b.k[1] = *(const bf16x8*)&Kh[(k0 + l15) * HD + 32 + lg * 8];
  b.k[2] = *(const bf16x8*)&Kh[(k0 + 16 + l15) * HD + lg * 8];
  b.k[3] = *(const bf16x8*)&Kh[(k0 + 16 + l15) * HD + 32 + lg * 8];
  const bf16* tile = V + ((size_t)(k0 >> 5) << 11);  // [64][32] contiguous
#pragma unroll
  for (int dt = 0; dt < 4; ++dt) {
    const bf16* base = tile + (dt * 16 + l15) * 32;
    uint2 lo = *(const uint2*)&base[4 * lg];
    uint2 hi = *(const uint2*)&base[16 + 4 * lg];
    b.v[dt][0] = lo.x; b.v[dt][1] = lo.y; b.v[dt][2] = hi.x; b.v[dt][3] = hi.y;
  }
}

// Swapped QK^T (mfma(K,Q)) -> lane holds P[q=l15][k]; packed lane-locally into the PV
// A-fragment under pi(8lg+j) = (j<4 ? 4lg+j : 16+4lg+j-4); V' fragments use the same pi.
// DIAG=false chunks (k0+32 <= q0) are provably fully unmasked -> no compare/select.
template <bool DIAG>
static __device__ __forceinline__ void kv_compute(const KV& b, int k0, int q0,
                                                  const bf16x8 (&qa)[4][2],
                                                  f32x4 (&acc)[4][4], int l15, int lg) {
  const int kb0i = k0 + lg * 4, kb1i = k0 + 16 + lg * 4;
#pragma unroll
  for (int qt = 0; qt < 4; ++qt) {
    f32x4 s0 = {}, s1 = {};
    s0 = mfma16(b.k[0], qa[qt][0], s0);
    s0 = mfma16(b.k[1], qa[qt][1], s0);
    s1 = mfma16(b.k[2], qa[qt][0], s1);
    s1 = mfma16(b.k[3], qa[qt][1], s1);
    const int qq = q0 + qt * 16 + l15;
    union { unsigned int u[4]; bf16x8 v; } pa;
#pragma unroll
    for (int hw = 0; hw < 2; ++hw) {
      bf16x2 t0, t1;
#pragma unroll
      for (int r = 0; r < 2; ++r) {
        int rr = hw * 2 + r;
        float p0 = fexp2(s0[rr]);
        float p1 = fexp2(s1[rr]);
        if (DIAG) {
          p0 = (kb0i + rr < qq) ? p0 : 0.f;
          p1 = (kb1i + rr < qq) ? p1 : 0.f;
        }
        t0[r] = (bf16)p0;
        t1[r] = (bf16)p1;
      }
      pa.u[hw] = __builtin_bit_cast(unsigned int, t0);
      pa.u[hw + 2] = __builtin_bit_cast(unsigned int, t1);
    }
#pragma unroll
    for (int dt = 0; dt < 4; ++dt) {
      union { unsigned int u[4]; bf16x8 v; } vf;
      vf.u[0] = b.v[dt][0]; vf.u[1] = b.v[dt][1];
      vf.u[2] = b.v[dt][2]; vf.u[3] = b.v[dt][3];
      acc[qt][dt] = mfma16(pa.v, vf.v, acc[qt][dt]);
    }
  }
}

// ---------------- pass B: 64q tiles paired (t, 31-t); k-split 8 ways across
// (2 blocks per pair) x (4 waves). Grid 1024, 256-thread blocks, VGPR-safe (256,2).
// Block kh writes a bf16 PARTIAL ctx (ctxP0 / ctxP1); ctxfin adds them + vlast.
__global__ __launch_bounds__(256, 2) void attn_ctx(const bf16* __restrict__ Qb,
                                                   const bf16* __restrict__ Kb,
                                                   const bf16* __restrict__ Vt,
                                                   bf16* __restrict__ ctxP0,
                                                   bf16* __restrict__ ctxP1) {
  __shared__ __align__(16) float red[2][64 * 68];  // [d][q] pitch 68 (34.8 KB)
  int bh, pr, kh;
  swz1024(blockIdx.x, bh, pr, kh);
  const int tid = threadIdx.x, l = tid & 63, w = tid >> 6;
  const int l15 = l & 15, lg = l >> 4;
  const int s = kh * 4 + w;  // k-slot 0..7
  const bf16* Q = Qb + (size_t)bh * SS * HD;
  const bf16* Kh = Kb + (size_t)bh * SS * HD;
  const bf16* V = Vt + (size_t)bh * SS * HD;  // tile-major [64][64][32], rz-prescaled
  bf16* ctxP = kh ? ctxP1 : ctxP0;
  const int b = bh >> 4, h = bh & 15;

  for (int half = 0; half < 2; ++half) {
    const int t = half ? (31 - pr) : pr;
    const int q0 = t * 64;

    bf16x8 qa[4][2];
#pragma unroll
    for (int qt = 0; qt < 4; ++qt)
#pragma unroll
      for (int kk = 0; kk < 2; ++kk)
        qa[qt][kk] = *(const bf16x8*)&Q[(q0 + qt * 16 + l15) * HD + kk * 32 + lg * 8];

    f32x4 acc[4][4] = {};  // [qt][dt]
    KV A;
    // unmasked chunks: k0 = s*32 + 256j < q0
    for (int k0 = s * 32; k0 < q0; k0 += 256) {
      kv_load(A, Kh, V, k0, l15, lg);
      kv_compute<false>(A, k0, q0, qa, acc, l15, lg);
    }
    // diagonal chunks k0 = q0, q0+32 -> slots (2t)&7 and (2t+1)&7
    {
      const int cw = (2 * t) & 7;
      int dk = (s == cw) ? q0 : ((s == ((cw + 1) & 7)) ? q0 + 32 : -1);
      if (dk >= 0) {
        kv_load(A, Kh, V, dk, l15, lg);
        kv_compute<true>(A, dk, q0, qa, acc, l15, lg);
      }
    }

    // merge 4 per-wave partials with 2 buffers: w1->bufA, w3->bufB; w0+=A, w2+=B;
    // then w2->bufA; w0+=A; w0 writes the block's partial ctx.
    if (w == 1 || w == 3) {
      float* buf = red[(w - 1) >> 1];
#pragma unroll
      for (int qt = 0; qt < 4; ++qt)
#pragma unroll
        for (int dt = 0; dt < 4; ++dt)
          *(f32x4*)&buf[(dt * 16 + l15) * 68 + qt * 16 + lg * 4] = acc[qt][dt];
    }
    __syncthreads();
    if (w == 0 || w == 2) {
      const float* buf = red[w >> 1];
#pragma unroll
      for (int qt = 0; qt < 4; ++qt)
#pragma unroll
        for (int dt = 0; dt < 4; ++dt)
          acc[qt][dt] += *(const f32x4*)&buf[(dt * 16 + l15) * 68 + qt * 16 + lg * 4];
    }
    __syncthreads();
    if (w == 2) {
#pragma unroll
      for (int qt = 0; qt < 4; ++qt)
#pragma unroll
        for (int dt = 0; dt < 4; ++dt)
          *(f32x4*)&red[0][(dt * 16 + l15) * 68 + qt * 16 + lg * 4] = acc[qt][dt];
    }
    __syncthreads();
    if (w == 0) {
#pragma unroll
      for (int qt = 0; qt < 4; ++qt) {
#pragma unroll
        for (int dt = 0; dt < 4; ++dt) {
          f32x4 a = acc[qt][dt];
          a += *(const f32x4*)&red[0][(dt * 16 + l15) * 68 + qt * 16 + lg * 4];
#pragma unroll
          for (int r = 0; r < 4; ++r) {
            int q = q0 + qt * 16 + lg * 4 + r;
            ctxP[((size_t)(b * SS + q)) * DD + h * HD + dt * 16 + l15] = (bf16)a[r];
          }
        }
      }
    }
    __syncthreads();  // protect red before next half reuses it
  }
}

// ---------------- combine partial ctx halves + vlast -> final bf16 ctx (in place on P0) -
__global__ __launch_bounds__(256) void ctxfin(const bf16* __restrict__ P1,
                                              const float* __restrict__ vlastB,
                                              bf16* __restrict__ ctx) {
  int i = blockIdx.x * 256 + threadIdx.x;  // bf16x8 index over [4096][1024]
  int e0 = i * 8;
  int row = e0 >> 10, col = e0 & (DD - 1);
  int b = row >> 11;
  int vidx = (b * HH + (col >> 6)) * 64 + (col & 63);
  bf16x8 p0 = ((const bf16x8*)ctx)[i];
  bf16x8 p1 = ((const bf16x8*)P1)[i];
  f32x4 v0 = *(const f32x4*)&vlastB[vidx];
  f32x4 v1 = *(const f32x4*)&vlastB[vidx + 4];
  bf16x8 o;
#pragma unroll
  for (int j = 0; j < 4; ++j) o[j] = (bf16)((float)p0[j] + (float)p1[j] + v0[j]);
#pragma unroll
  for (int j = 0; j < 4; ++j) o[4 + j] = (bf16)((float)p0[4 + j] + (float)p1[4 + j] + v1[j]);
  ((bf16x8*)ctx)[i] = o;
}

// ---------------- launcher ----------------
extern "C" void kernel_launch(void* const* d_in, const int* in_sizes, int n_in,
                              void* d_out, int out_size, void* d_ws, size_t ws_size,
                              hipStream_t stream) {
  const float* q  = (const float*)d_in[0];
  const float* k  = (const float*)d_in[1];
  const float* v  = (const float*)d_in[2];
  const float* Wq = (const float*)d_in[3];
  const float* bq = (const float*)d_in[4];
  const float* Wk = (const float*)d_in[5];
  const float* bk = (const float*)d_in[6];
  const float* Wv = (const float*)d_in[7];
  const float* bv = (const float*)d_in[8];
  const float* Wo = (const float*)d_in[9];
  const float* bo = (const float*)d_in[10];

  char* ws = (char*)d_ws;
  const size_t SZP = (size_t)4096 * 1024 * 2;  // 8 MiB
  const size_t SZW = (size_t)1024 * 1024 * 2;  // 2 MiB
  bf16* Qb   = (bf16*)(ws + 0 * SZP);          // [BH][S][64] (prescaled)
  bf16* Kb   = (bf16*)(ws + 1 * SZP);          // [BH][S][64]
  bf16* Vt   = (bf16*)(ws + 2 * SZP);          // [BH][64][64][32] tile-major (rz-prescaled)
  bf16* ctxb = (bf16*)(ws + 3 * SZP);          // [B][S][D]; also ctx partial 0
  bf16* qb16 = (bf16*)(ws + 4 * SZP);          // dead after proj_gemm -> ctx partial 1
  bf16* kb16 = (bf16*)(ws + 5 * SZP);
  bf16* vb16 = (bf16*)(ws + 6 * SZP);
  bf16* Wqb  = (bf16*)(ws + 7 * SZP + 0 * SZW);
  bf16* Wkb  = (bf16*)(ws + 7 * SZP + 1 * SZW);
  bf16* Wvb  = (bf16*)(ws + 7 * SZP + 2 * SZW);
  bf16* Wob  = (bf16*)(ws + 7 * SZP + 3 * SZW);
  float* zPart = (float*)(ws + 7 * SZP + 4 * SZW);     // [2][BH][SS] fp32
  float* cRZ   = zPart + (size_t)2 * BH * SS;          // [BH][SS] fp32
  float* vlastB = cRZ + (size_t)BH * SS;               // [BH][64] fp32
  bf16* ctxP1 = qb16;                                  // reuse input-x bf16 region

  cvt_w<<<dim3(512, 4), 256, 0, stream>>>(Wq, Wk, Wv, Wo, Wqb, Wkb, Wvb, Wob);
  cvt_x<<<dim3(2048, 3), 256, 0, stream>>>(q, k, v, qb16, kb16, vb16);

  proj_gemm<<<dim3(1024 / 128, 4096 / 128, 3), 256, 0, stream>>>(
      qb16, kb16, vb16, Wqb, Wkb, Wvb, bq, bk, bv, Qb, Kb, Vt);

  colz<<<1024, 256, 0, stream>>>(Qb, Kb, zPart);
  rzfin<<<(BH * SS / 4) / 256, 256, 0, stream>>>(zPart, cRZ);
  vscale<<<(BH * HD * SS / 8) / 256, 256, 0, stream>>>(Vt, cRZ, vlastB);
  attn_ctx<<<1024, 256, 0, stream>>>(Qb, Kb, Vt, ctxb, ctxP1);
  ctxfin<<<(4096 * 1024 / 8) / 256, 256, 0, stream>>>(ctxP1, vlastB, ctxb);

  out_gemm<<<dim3(1024 / 128, 4096 / 128), 256, 0, stream>>>(ctxb, Wob, bo, (float*)d_out);
}